// Round 4
// baseline (347.011 us; speedup 1.0000x reference)
//
#include <hip/hip_runtime.h>

#define T_TOK 2048
#define DIM   512
#define MOE   256
#define NE    64
#define NG    8
#define TOPKG 4
#define TOPK  8
#define CAP   1024
#define MOE_SCALE 2.5f

typedef float f32x4 __attribute__((ext_vector_type(4)));
typedef short s16x8 __attribute__((ext_vector_type(8)));

__device__ __forceinline__ unsigned short f2bf(float f) {
    unsigned u = __builtin_bit_cast(unsigned, f);
    unsigned r = (u + 0x7fffu + ((u >> 16) & 1u)) >> 16;
    return (unsigned short)r;
}

// ---------------- Fused gating: scores + grouped top-k, one wave per token ----
__global__ __launch_bounds__(256) void gate_fused_k(const float* __restrict__ x,
                                                    const float* __restrict__ gw,
                                                    const float* __restrict__ gb,
                                                    int* __restrict__ counts,
                                                    int* __restrict__ etok,
                                                    float* __restrict__ wt_of)
{
    int t = blockIdx.x * 4 + (threadIdx.x >> 6);
    int lane = threadIdx.x & 63;

    // lane e: dot(x[t], gw[e]) over 512
    const float4* xr = (const float4*)(x + (size_t)t * DIM);
    const float4* wr = (const float4*)(gw + (size_t)lane * DIM);
    float acc = 0.f;
#pragma unroll 8
    for (int i = 0; i < DIM / 4; ++i) {
        float4 xa = xr[i], wa = wr[i];
        acc += xa.x * wa.x + xa.y * wa.y + xa.z * wa.z + xa.w * wa.w;
    }
    float sc = 1.f / (1.f + __expf(-acc));   // pre-bias score
    float s  = sc + gb[lane];                 // biased score

    // group top-2 sum within each 8-lane group (merge (m1,m2) pairs)
    float m1 = s, m2 = -1e30f;
#pragma unroll
    for (int d = 1; d < 8; d <<= 1) {
        float o1 = __shfl_xor(m1, d);
        float o2 = __shfl_xor(m2, d);
        float n1 = fmaxf(m1, o1);
        float n2 = fmaxf(fminf(m1, o1), fmaxf(m2, o2));
        m1 = n1; m2 = n2;
    }
    float gv = m1 + m2;   // uniform within group

    // top-4 groups (tie -> lowest group index)
    bool gkeep = false;
#pragma unroll
    for (int it = 0; it < TOPKG; ++it) {
        float m = gv;
#pragma unroll
        for (int d = 1; d < 64; d <<= 1) m = fmaxf(m, __shfl_xor(m, d));
        unsigned long long mask = __ballot(gv == m);
        int ldr = __ffsll(mask) - 1;
        if ((lane >> 3) == (ldr >> 3)) { gkeep = true; gv = -2e30f; }
    }
    float sv = gkeep ? s : -1e30f;

    // top-8 experts (tie -> lowest index); lane k keeps k-th winner
    float wsum = 0.f;
    int my_e = 0; float my_w = 0.f;
#pragma unroll
    for (int k = 0; k < TOPK; ++k) {
        float m = sv;
#pragma unroll
        for (int d = 1; d < 64; d <<= 1) m = fmaxf(m, __shfl_xor(m, d));
        unsigned long long mask = __ballot(sv == m);
        int l = __ffsll(mask) - 1;
        float wk = __shfl(sc, l);
        wsum += wk;
        if (lane == k) { my_e = l; my_w = wk; }
        if (lane == l) sv = -2e30f;
    }
    float scale = MOE_SCALE / wsum;
    if (lane < TOPK) {
        int p = atomicAdd(&counts[my_e], 1);
        int rid = t * TOPK + lane;           // global slot id
        bool ok = (p < CAP);
        if (ok) etok[my_e * CAP + p] = rid;
        wt_of[rid] = ok ? my_w * scale : 0.f;
    }
}

// ---------------- Weight conversion: fp32 -> bf16 in B-frag-major layout -------
// Frag (16 n x 32 k): element (lane, j) = W[k0 + (lane>>4)*8 + j][n0 + (lane&15)]
// Frag storage: 64 lanes x 8 bf16 contiguous (1 KB). Frag order within expert:
// GEMM1 (w1/w3, k=DIM, n=MOE): idx = nt*16 + kt  (nt<16, kt<16)
// GEMM2 (w2,    k=MOE, n=DIM): idx = nt*8  + kt  (nt<32, kt<8)
__global__ __launch_bounds__(256) void convert_w_k(const float* __restrict__ w1,
                                                   const float* __restrict__ w3,
                                                   const float* __restrict__ w2,
                                                   short* __restrict__ ws1,
                                                   short* __restrict__ ws3,
                                                   short* __restrict__ ws2)
{
    int Wv = blockIdx.x * 4 + (threadIdx.x >> 6);
    int lane = threadIdx.x & 63;
    int q = lane >> 4, m16 = lane & 15;

    const float* src;
    short* dst;
    int ldw;
    if (Wv < 16384) {
        int e = Wv >> 8, rem = Wv & 255, nt = rem >> 4, kt = rem & 15;
        src = w1 + ((size_t)e * DIM + kt * 32 + q * 8) * MOE + nt * 16 + m16;
        dst = ws1 + (size_t)Wv * 512 + lane * 8;
        ldw = MOE;
    } else if (Wv < 32768) {
        int V = Wv - 16384;
        int e = V >> 8, rem = V & 255, nt = rem >> 4, kt = rem & 15;
        src = w3 + ((size_t)e * DIM + kt * 32 + q * 8) * MOE + nt * 16 + m16;
        dst = ws3 + (size_t)V * 512 + lane * 8;
        ldw = MOE;
    } else {
        int V = Wv - 32768;
        int e = V >> 8, rem = V & 255, nt = rem >> 3, kt = rem & 7;
        src = w2 + ((size_t)e * MOE + kt * 32 + q * 8) * DIM + nt * 16 + m16;
        dst = ws2 + (size_t)V * 512 + lane * 8;
        ldw = DIM;
    }
    short o[8];
#pragma unroll
    for (int j = 0; j < 8; ++j) o[j] = (short)f2bf(src[(size_t)j * ldw]);
    *(s16x8*)dst = *(const s16x8*)o;
}

// ---------------- FFN grouped GEMM (B-frags direct from global) ---------------
__global__ __launch_bounds__(256) void ffn_kernel(const float* __restrict__ x,
                                                  const short* __restrict__ ws1,
                                                  const short* __restrict__ ws3,
                                                  const short* __restrict__ ws2,
                                                  const int* __restrict__ counts,
                                                  const int* __restrict__ etok,
                                                  short* __restrict__ ybuf)
{
    __shared__ short Xa[32 * 520];   // 32 tokens x 512 bf16, stride 520 (reused as y-tile)
    __shared__ short Ht[32 * 264];   // 32 tokens x 256 bf16, stride 264
    __shared__ int   rid_s[32];

    int e    = blockIdx.x & 63;
    int tile = blockIdx.x >> 6;
    int n_e  = min(counts[e], CAP);
    int r0   = tile * 32;
    if (r0 >= n_e) return;
    int nrows = min(32, n_e - r0);

    int tid = threadIdx.x;
    if (tid < 32)
        rid_s[tid] = (tid < nrows) ? etok[e * CAP + r0 + tid] : -1;
    {
        // 8 threads per token row; each converts 64 fp32 -> 64 bf16
        int r = tid >> 3, c = tid & 7;
        short* dst = Xa + r * 520 + c * 64;
        if (r < nrows) {
            int tok = etok[e * CAP + r0 + r] >> 3;
            const float4* src = (const float4*)(x + (size_t)tok * DIM + c * 64);
#pragma unroll
            for (int i = 0; i < 16; ++i) {
                float4 f = src[i];
                short4 o;
                o.x = (short)f2bf(f.x); o.y = (short)f2bf(f.y);
                o.z = (short)f2bf(f.z); o.w = (short)f2bf(f.w);
                *(short4*)(dst + i * 4) = o;
            }
        } else {
            short4 z = {0, 0, 0, 0};
#pragma unroll
            for (int i = 0; i < 16; ++i) *(short4*)(dst + i * 4) = z;
        }
    }
    __syncthreads();

    int w = tid >> 6, lane = tid & 63;
    int q = lane >> 4, m16 = lane & 15;
    const int laneoff = lane * 8;

    // ---------------- GEMM1: h1 = X@W1, h3 = X@W3 (wave: 64 n-cols) ----------
    f32x4 acc1[2][4], acc3[2][4];
#pragma unroll
    for (int i = 0; i < 2; ++i)
#pragma unroll
        for (int j = 0; j < 4; ++j) { acc1[i][j] = (f32x4)0.f; acc3[i][j] = (f32x4)0.f; }

    const short* B1 = ws1 + ((size_t)e * 256 + (size_t)w * 4 * 16) * 512 + laneoff;
    const short* B3 = ws3 + ((size_t)e * 256 + (size_t)w * 4 * 16) * 512 + laneoff;
    const short* Arow0 = Xa + m16 * 520 + q * 8;
    const short* Arow1 = Xa + (16 + m16) * 520 + q * 8;

    s16x8 b1a[4], b3a[4], b1b[4], b3b[4], a0a, a1a, a0b, a1b;
#pragma unroll
    for (int nt = 0; nt < 4; ++nt) {
        b1a[nt] = *(const s16x8*)(B1 + (nt * 16) * 512);
        b3a[nt] = *(const s16x8*)(B3 + (nt * 16) * 512);
    }
    a0a = *(const s16x8*)(Arow0);
    a1a = *(const s16x8*)(Arow1);

#pragma unroll
    for (int kt = 0; kt < 16; kt += 2) {
        // prefetch kt+1
#pragma unroll
        for (int nt = 0; nt < 4; ++nt) {
            b1b[nt] = *(const s16x8*)(B1 + (nt * 16 + kt + 1) * 512);
            b3b[nt] = *(const s16x8*)(B3 + (nt * 16 + kt + 1) * 512);
        }
        a0b = *(const s16x8*)(Arow0 + (kt + 1) * 32);
        a1b = *(const s16x8*)(Arow1 + (kt + 1) * 32);
        // compute kt
#pragma unroll
        for (int nt = 0; nt < 4; ++nt) {
            acc1[0][nt] = __builtin_amdgcn_mfma_f32_16x16x32_bf16(a0a, b1a[nt], acc1[0][nt], 0, 0, 0);
            acc1[1][nt] = __builtin_amdgcn_mfma_f32_16x16x32_bf16(a1a, b1a[nt], acc1[1][nt], 0, 0, 0);
            acc3[0][nt] = __builtin_amdgcn_mfma_f32_16x16x32_bf16(a0a, b3a[nt], acc3[0][nt], 0, 0, 0);
            acc3[1][nt] = __builtin_amdgcn_mfma_f32_16x16x32_bf16(a1a, b3a[nt], acc3[1][nt], 0, 0, 0);
        }
        // prefetch kt+2
        if (kt + 2 < 16) {
#pragma unroll
            for (int nt = 0; nt < 4; ++nt) {
                b1a[nt] = *(const s16x8*)(B1 + (nt * 16 + kt + 2) * 512);
                b3a[nt] = *(const s16x8*)(B3 + (nt * 16 + kt + 2) * 512);
            }
            a0a = *(const s16x8*)(Arow0 + (kt + 2) * 32);
            a1a = *(const s16x8*)(Arow1 + (kt + 2) * 32);
        }
        // compute kt+1
#pragma unroll
        for (int nt = 0; nt < 4; ++nt) {
            acc1[0][nt] = __builtin_amdgcn_mfma_f32_16x16x32_bf16(a0b, b1b[nt], acc1[0][nt], 0, 0, 0);
            acc1[1][nt] = __builtin_amdgcn_mfma_f32_16x16x32_bf16(a1b, b1b[nt], acc1[1][nt], 0, 0, 0);
            acc3[0][nt] = __builtin_amdgcn_mfma_f32_16x16x32_bf16(a0b, b3b[nt], acc3[0][nt], 0, 0, 0);
            acc3[1][nt] = __builtin_amdgcn_mfma_f32_16x16x32_bf16(a1b, b3b[nt], acc3[1][nt], 0, 0, 0);
        }
    }

    // SwiGLU -> Ht (bf16); h col m = w*64 + nt*16 + m16, row t = mt*16 + q*4 + r
#pragma unroll
    for (int mt = 0; mt < 2; ++mt)
#pragma unroll
        for (int nt = 0; nt < 4; ++nt)
#pragma unroll
            for (int r = 0; r < 4; ++r) {
                float g = acc1[mt][nt][r];
                float u = acc3[mt][nt][r];
                float hv = g / (1.f + __expf(-g)) * u;
                int t = mt * 16 + q * 4 + r;
                int m = w * 64 + nt * 16 + m16;
                Ht[t * 264 + m] = (short)f2bf(hv);
            }
    __syncthreads();

    // ---------------- GEMM2: Y = H@W2 (wave: 128 n-cols, 8 n-tiles) ----------
    f32x4 acc2[2][8];
#pragma unroll
    for (int i = 0; i < 2; ++i)
#pragma unroll
        for (int j = 0; j < 8; ++j) acc2[i][j] = (f32x4)0.f;

    const short* B2 = ws2 + ((size_t)e * 256 + (size_t)w * 8 * 8) * 512 + laneoff;
    const short* Hrow0 = Ht + m16 * 264 + q * 8;
    const short* Hrow1 = Ht + (16 + m16) * 264 + q * 8;

    s16x8 c2a[8], c2b[8], h0a, h1a, h0b, h1b;
#pragma unroll
    for (int nt = 0; nt < 8; ++nt) c2a[nt] = *(const s16x8*)(B2 + (nt * 8) * 512);
    h0a = *(const s16x8*)(Hrow0);
    h1a = *(const s16x8*)(Hrow1);

#pragma unroll
    for (int kt = 0; kt < 8; kt += 2) {
#pragma unroll
        for (int nt = 0; nt < 8; ++nt)
            c2b[nt] = *(const s16x8*)(B2 + (nt * 8 + kt + 1) * 512);
        h0b = *(const s16x8*)(Hrow0 + (kt + 1) * 32);
        h1b = *(const s16x8*)(Hrow1 + (kt + 1) * 32);
#pragma unroll
        for (int nt = 0; nt < 8; ++nt) {
            acc2[0][nt] = __builtin_amdgcn_mfma_f32_16x16x32_bf16(h0a, c2a[nt], acc2[0][nt], 0, 0, 0);
            acc2[1][nt] = __builtin_amdgcn_mfma_f32_16x16x32_bf16(h1a, c2a[nt], acc2[1][nt], 0, 0, 0);
        }
        if (kt + 2 < 8) {
#pragma unroll
            for (int nt = 0; nt < 8; ++nt)
                c2a[nt] = *(const s16x8*)(B2 + (nt * 8 + kt + 2) * 512);
            h0a = *(const s16x8*)(Hrow0 + (kt + 2) * 32);
            h1a = *(const s16x8*)(Hrow1 + (kt + 2) * 32);
        }
#pragma unroll
        for (int nt = 0; nt < 8; ++nt) {
            acc2[0][nt] = __builtin_amdgcn_mfma_f32_16x16x32_bf16(h0b, c2b[nt], acc2[0][nt], 0, 0, 0);
            acc2[1][nt] = __builtin_amdgcn_mfma_f32_16x16x32_bf16(h1b, c2b[nt], acc2[1][nt], 0, 0, 0);
        }
    }

    // epilogue: y tile (bf16) -> LDS (reuse Xa), then coalesced row stores
    short* ylds = Xa;   // [32][520]
#pragma unroll
    for (int mt = 0; mt < 2; ++mt)
#pragma unroll
        for (int nt = 0; nt < 8; ++nt)
#pragma unroll
            for (int r = 0; r < 4; ++r) {
                int t = mt * 16 + q * 4 + r;
                int d = (w * 8 + nt) * 16 + m16;
                ylds[t * 520 + d] = (short)f2bf(acc2[mt][nt][r]);
            }
    __syncthreads();
    {
        int r = tid >> 3, c = tid & 7;   // 8 threads/row, 128 B each
        if (r < nrows) {
            int rid = rid_s[r];
            int4* dst = (int4*)(ybuf + (size_t)rid * DIM);
            const int4* srcl = (const int4*)(ylds + r * 520 + c * 64);
#pragma unroll
            for (int i = 0; i < 8; ++i) dst[c * 8 + i] = srcl[i];
        }
    }
}

// ---------------- Combine: out[t] = sum_k wt[t,k] * ybuf[t*8+k] ---------------
__global__ __launch_bounds__(256) void combine_k(const short* __restrict__ ybuf,
                                                 const float* __restrict__ wt_of,
                                                 float* __restrict__ out)
{
    int t = blockIdx.x;
    int tid = threadIdx.x;
    const int* yb = (const int*)ybuf;
    float sx = 0.f, sy = 0.f;
#pragma unroll
    for (int k = 0; k < TOPK; ++k) {
        float wk = wt_of[t * TOPK + k];
        int v = yb[(size_t)(t * TOPK + k) * (DIM / 2) + tid];
        float lo = __builtin_bit_cast(float, (unsigned)v << 16);
        float hi = __builtin_bit_cast(float, (unsigned)v & 0xffff0000u);
        sx += wk * lo;
        sy += wk * hi;
    }
    float2 o = {sx, sy};
    ((float2*)out)[(size_t)t * (DIM / 2) + tid] = o;
}

extern "C" void kernel_launch(void* const* d_in, const int* in_sizes, int n_in,
                              void* d_out, int out_size, void* d_ws, size_t ws_size,
                              hipStream_t stream)
{
    const float* x  = (const float*)d_in[0];
    const float* gw = (const float*)d_in[1];
    const float* gb = (const float*)d_in[2];
    const float* w1 = (const float*)d_in[3];
    const float* w3 = (const float*)d_in[4];
    const float* w2 = (const float*)d_in[5];

    char* ws = (char*)d_ws;
    short* ws1   = (short*)(ws);                     // 16,777,216 B
    short* ws3   = (short*)(ws + 16777216);          // 16,777,216 B
    short* ws2   = (short*)(ws + 33554432);          // 16,777,216 B
    short* ybuf  = (short*)(ws + 50331648);          // 16384*512*2 = 16,777,216 B
    int*   etok  = (int*)  (ws + 67108864);          // 262,144 B
    float* wt_of = (float*)(ws + 67371008);          // 65,536 B
    int*   counts= (int*)  (ws + 67436544);          // 256 B

    hipMemsetAsync(counts, 0, NE * 4, stream);

    convert_w_k<<<12288, 256, 0, stream>>>(w1, w3, w2, ws1, ws3, ws2);
    gate_fused_k<<<T_TOK / 4, 256, 0, stream>>>(x, gw, gb, counts, etok, wt_of);
    ffn_kernel<<<NE * (CAP / 32), 256, 0, stream>>>(x, ws1, ws3, ws2,
                                                    counts, etok, ybuf);
    combine_k<<<T_TOK, 256, 0, stream>>>(ybuf, wt_of, (float*)d_out);
}

// Round 5
// 341.396 us; speedup vs baseline: 1.0164x; 1.0164x over previous
//
#include <hip/hip_runtime.h>

#define T_TOK 2048
#define DIM   512
#define MOE   256
#define NE    64
#define NG    8
#define TOPKG 4
#define TOPK  8
#define CAP   1024
#define MOE_SCALE 2.5f

typedef float f32x4 __attribute__((ext_vector_type(4)));
typedef short s16x8 __attribute__((ext_vector_type(8)));

__device__ __forceinline__ unsigned short f2bf(float f) {
    unsigned u = __builtin_bit_cast(unsigned, f);
    unsigned r = (u + 0x7fffu + ((u >> 16) & 1u)) >> 16;
    return (unsigned short)r;
}

// ---------------- x fp32 -> bf16 (row-major) ----------------
__global__ __launch_bounds__(256) void xconv_k(const float* __restrict__ x,
                                               short* __restrict__ xb)
{
    int i = (blockIdx.x * 256 + threadIdx.x) * 4;
    float4 v = *(const float4*)(x + i);
    short4 o;
    o.x = (short)f2bf(v.x); o.y = (short)f2bf(v.y);
    o.z = (short)f2bf(v.z); o.w = (short)f2bf(v.w);
    *(short4*)(xb + i) = o;
}

// ---------------- Fused gating: scores + grouped top-k, one wave per token ----
__global__ __launch_bounds__(256) void gate_fused_k(const float* __restrict__ x,
                                                    const float* __restrict__ gw,
                                                    const float* __restrict__ gb,
                                                    int* __restrict__ counts,
                                                    int* __restrict__ etok,
                                                    float* __restrict__ wt_of)
{
    int t = blockIdx.x * 4 + (threadIdx.x >> 6);
    int lane = threadIdx.x & 63;

    const float4* xr = (const float4*)(x + (size_t)t * DIM);
    const float4* wr = (const float4*)(gw + (size_t)lane * DIM);
    float acc = 0.f;
#pragma unroll 8
    for (int i = 0; i < DIM / 4; ++i) {
        float4 xa = xr[i], wa = wr[i];
        acc += xa.x * wa.x + xa.y * wa.y + xa.z * wa.z + xa.w * wa.w;
    }
    float sc = 1.f / (1.f + __expf(-acc));   // pre-bias score
    float s  = sc + gb[lane];                 // biased score

    // group top-2 sum within each 8-lane group
    float m1 = s, m2 = -1e30f;
#pragma unroll
    for (int d = 1; d < 8; d <<= 1) {
        float o1 = __shfl_xor(m1, d);
        float o2 = __shfl_xor(m2, d);
        float n1 = fmaxf(m1, o1);
        float n2 = fmaxf(fminf(m1, o1), fmaxf(m2, o2));
        m1 = n1; m2 = n2;
    }
    float gv = m1 + m2;

    // top-4 groups (tie -> lowest group index)
    bool gkeep = false;
#pragma unroll
    for (int it = 0; it < TOPKG; ++it) {
        float m = gv;
#pragma unroll
        for (int d = 1; d < 64; d <<= 1) m = fmaxf(m, __shfl_xor(m, d));
        unsigned long long mask = __ballot(gv == m);
        int ldr = __ffsll(mask) - 1;
        if ((lane >> 3) == (ldr >> 3)) { gkeep = true; gv = -2e30f; }
    }
    float sv = gkeep ? s : -1e30f;

    // top-8 experts (tie -> lowest index)
    float wsum = 0.f;
    int my_e = 0; float my_w = 0.f;
#pragma unroll
    for (int k = 0; k < TOPK; ++k) {
        float m = sv;
#pragma unroll
        for (int d = 1; d < 64; d <<= 1) m = fmaxf(m, __shfl_xor(m, d));
        unsigned long long mask = __ballot(sv == m);
        int l = __ffsll(mask) - 1;
        float wk = __shfl(sc, l);
        wsum += wk;
        if (lane == k) { my_e = l; my_w = wk; }
        if (lane == l) sv = -2e30f;
    }
    float scale = MOE_SCALE / wsum;
    if (lane < TOPK) {
        int p = atomicAdd(&counts[my_e], 1);
        int rid = t * TOPK + lane;           // global slot id
        bool ok = (p < CAP);
        if (ok) etok[my_e * CAP + p] = rid;
        wt_of[rid] = ok ? my_w * scale : 0.f;
    }
}

// ---------------- K1: h = silu(X@W1) * (X@W3), weight-stationary -------------
// Wave = (expert, 16-col slice of MOE, token-half). B-frags for the slice are
// converted fp32->bf16 once into 128 VGPRs; inner loop is 2 A-gathers + 4 MFMA
// per kt — no LDS, no barriers, weights read once per wave.
__global__ __launch_bounds__(256) void gemm1_k(const short* __restrict__ xb,
                                               const float* __restrict__ w1,
                                               const float* __restrict__ w3,
                                               const int* __restrict__ counts,
                                               const int* __restrict__ etok,
                                               short* __restrict__ hbuf)
{
    int e = blockIdx.x >> 3, sub = blockIdx.x & 7;
    int w = threadIdx.x >> 6, lane = threadIdx.x & 63;
    int slice = sub * 2 + (w & 1);      // 0..15
    int half  = w >> 1;                 // 0..1
    int q = lane >> 4, m16 = lane & 15;
    int n0 = slice * 16;

    // B-init: lane holds col n0+m16, k = kt*32 + q*8 + j
    const float* W1c = w1 + (size_t)e * DIM * MOE + n0 + m16;
    const float* W3c = w3 + (size_t)e * DIM * MOE + n0 + m16;
    s16x8 B1f[16], B3f[16];
#pragma unroll
    for (int kt = 0; kt < 16; ++kt) {
        short t1[8], t3[8];
#pragma unroll
        for (int j = 0; j < 8; ++j) {
            size_t k = (size_t)(kt * 32 + q * 8 + j) * MOE;
            t1[j] = (short)f2bf(W1c[k]);
            t3[j] = (short)f2bf(W3c[k]);
        }
        B1f[kt] = *(const s16x8*)t1;
        B3f[kt] = *(const s16x8*)t3;
    }

    int n_e = min(counts[e], CAP);
    int ntiles = (n_e + 31) >> 5;
    const int* el = etok + e * CAP;

    for (int tile = half; tile < ntiles; tile += 2) {
        int r0 = tile * 32;
        int nrows = min(32, n_e - r0);
        int rid0 = el[r0 + ((m16 < nrows) ? m16 : 0)];
        int rid1 = el[r0 + ((16 + m16 < nrows) ? 16 + m16 : 0)];
        const short* A0 = xb + (size_t)(rid0 >> 3) * DIM;
        const short* A1 = xb + (size_t)(rid1 >> 3) * DIM;

        f32x4 c1m0 = (f32x4)0.f, c1m1 = (f32x4)0.f;
        f32x4 c3m0 = (f32x4)0.f, c3m1 = (f32x4)0.f;
#pragma unroll
        for (int kt = 0; kt < 16; ++kt) {
            s16x8 a0 = *(const s16x8*)(A0 + kt * 32 + q * 8);
            s16x8 a1 = *(const s16x8*)(A1 + kt * 32 + q * 8);
            c1m0 = __builtin_amdgcn_mfma_f32_16x16x32_bf16(a0, B1f[kt], c1m0, 0, 0, 0);
            c1m1 = __builtin_amdgcn_mfma_f32_16x16x32_bf16(a1, B1f[kt], c1m1, 0, 0, 0);
            c3m0 = __builtin_amdgcn_mfma_f32_16x16x32_bf16(a0, B3f[kt], c3m0, 0, 0, 0);
            c3m1 = __builtin_amdgcn_mfma_f32_16x16x32_bf16(a1, B3f[kt], c3m1, 0, 0, 0);
        }
        // SwiGLU + store; C layout: row = q*4 + r (+16 for m1), col = m16
#pragma unroll
        for (int r = 0; r < 4; ++r) {
            int row0 = q * 4 + r;
            float g0 = c1m0[r], u0 = c3m0[r];
            float h0 = g0 / (1.f + __expf(-g0)) * u0;
            if (row0 < nrows)
                hbuf[(size_t)el[r0 + row0] * MOE + n0 + m16] = (short)f2bf(h0);
            int row1 = 16 + q * 4 + r;
            float g1 = c1m1[r], u1 = c3m1[r];
            float h1 = g1 / (1.f + __expf(-g1)) * u1;
            if (row1 < nrows)
                hbuf[(size_t)el[r0 + row1] * MOE + n0 + m16] = (short)f2bf(h1);
        }
    }
}

// ---------------- K2: y = H@W2, weight-stationary ----------------------------
__global__ __launch_bounds__(256) void gemm2_k(const short* __restrict__ hbuf,
                                               const float* __restrict__ w2,
                                               const int* __restrict__ counts,
                                               const int* __restrict__ etok,
                                               short* __restrict__ ybuf)
{
    int e = blockIdx.x >> 4, sub = blockIdx.x & 15;
    int w = threadIdx.x >> 6, lane = threadIdx.x & 63;
    int slice = sub * 2 + (w & 1);      // 0..31
    int half  = w >> 1;
    int q = lane >> 4, m16 = lane & 15;
    int n0 = slice * 16;                // of DIM

    const float* W2c = w2 + (size_t)e * MOE * DIM + n0 + m16;
    s16x8 B2f[8];
#pragma unroll
    for (int kt = 0; kt < 8; ++kt) {
        short t2[8];
#pragma unroll
        for (int j = 0; j < 8; ++j)
            t2[j] = (short)f2bf(W2c[(size_t)(kt * 32 + q * 8 + j) * DIM]);
        B2f[kt] = *(const s16x8*)t2;
    }

    int n_e = min(counts[e], CAP);
    int ntiles = (n_e + 31) >> 5;
    const int* el = etok + e * CAP;

    for (int tile = half; tile < ntiles; tile += 2) {
        int r0 = tile * 32;
        int nrows = min(32, n_e - r0);
        int rid0 = el[r0 + ((m16 < nrows) ? m16 : 0)];
        int rid1 = el[r0 + ((16 + m16 < nrows) ? 16 + m16 : 0)];
        const short* A0 = hbuf + (size_t)rid0 * MOE;
        const short* A1 = hbuf + (size_t)rid1 * MOE;

        f32x4 cm0 = (f32x4)0.f, cm1 = (f32x4)0.f;
#pragma unroll
        for (int kt = 0; kt < 8; ++kt) {
            s16x8 a0 = *(const s16x8*)(A0 + kt * 32 + q * 8);
            s16x8 a1 = *(const s16x8*)(A1 + kt * 32 + q * 8);
            cm0 = __builtin_amdgcn_mfma_f32_16x16x32_bf16(a0, B2f[kt], cm0, 0, 0, 0);
            cm1 = __builtin_amdgcn_mfma_f32_16x16x32_bf16(a1, B2f[kt], cm1, 0, 0, 0);
        }
#pragma unroll
        for (int r = 0; r < 4; ++r) {
            int row0 = q * 4 + r;
            if (row0 < nrows)
                ybuf[(size_t)el[r0 + row0] * DIM + n0 + m16] = (short)f2bf(cm0[r]);
            int row1 = 16 + q * 4 + r;
            if (row1 < nrows)
                ybuf[(size_t)el[r0 + row1] * DIM + n0 + m16] = (short)f2bf(cm1[r]);
        }
    }
}

// ---------------- Combine: out[t] = sum_k wt[t,k] * ybuf[t*8+k] ---------------
__global__ __launch_bounds__(256) void combine_k(const short* __restrict__ ybuf,
                                                 const float* __restrict__ wt_of,
                                                 float* __restrict__ out)
{
    int t = blockIdx.x;
    int tid = threadIdx.x;
    const int* yb = (const int*)ybuf;
    float sx = 0.f, sy = 0.f;
#pragma unroll
    for (int k = 0; k < TOPK; ++k) {
        float wk = wt_of[t * TOPK + k];
        int v = yb[(size_t)(t * TOPK + k) * (DIM / 2) + tid];
        float lo = __builtin_bit_cast(float, (unsigned)v << 16);
        float hi = __builtin_bit_cast(float, (unsigned)v & 0xffff0000u);
        sx += wk * lo;
        sy += wk * hi;
    }
    float2 o = {sx, sy};
    ((float2*)out)[(size_t)t * (DIM / 2) + tid] = o;
}

extern "C" void kernel_launch(void* const* d_in, const int* in_sizes, int n_in,
                              void* d_out, int out_size, void* d_ws, size_t ws_size,
                              hipStream_t stream)
{
    const float* x  = (const float*)d_in[0];
    const float* gw = (const float*)d_in[1];
    const float* gb = (const float*)d_in[2];
    const float* w1 = (const float*)d_in[3];
    const float* w3 = (const float*)d_in[4];
    const float* w2 = (const float*)d_in[5];

    char* ws = (char*)d_ws;
    short* xb    = (short*)(ws);                     // 2048*512*2   =  2,097,152
    short* hbuf  = (short*)(ws + 2097152);           // 16384*256*2  =  8,388,608
    short* ybuf  = (short*)(ws + 10485760);          // 16384*512*2  = 16,777,216
    int*   etok  = (int*)  (ws + 27262976);          // 64*1024*4    =    262,144
    float* wt_of = (float*)(ws + 27525120);          // 16384*4      =     65,536
    int*   counts= (int*)  (ws + 27590656);          // 256

    hipMemsetAsync(counts, 0, NE * 4, stream);

    xconv_k<<<(T_TOK * DIM) / (256 * 4), 256, 0, stream>>>(x, xb);
    gate_fused_k<<<T_TOK / 4, 256, 0, stream>>>(x, gw, gb, counts, etok, wt_of);
    gemm1_k<<<NE * 8, 256, 0, stream>>>(xb, w1, w3, counts, etok, hbuf);
    gemm2_k<<<NE * 16, 256, 0, stream>>>(hbuf, w2, counts, etok, ybuf);
    combine_k<<<T_TOK, 256, 0, stream>>>(ybuf, wt_of, (float*)d_out);
}